// Round 3
// baseline (515.187 us; speedup 1.0000x reference)
//
#include <hip/hip_runtime.h>

typedef unsigned short u16;
typedef short s16x8 __attribute__((ext_vector_type(8)));
typedef float f32x4 __attribute__((ext_vector_type(4)));
typedef float f32x2 __attribute__((ext_vector_type(2)));

#define NNODES 55296
#define NEDGES 221184
#define ROWS   110592   // B * NNODES
#define MFMA   __builtin_amdgcn_mfma_f32_16x16x32_bf16

__device__ __forceinline__ u16 f2bf(float f) {
    union { float f; unsigned u; } v; v.f = f;
    unsigned r = (v.u + 0x7fffu + ((v.u >> 16) & 1u)) >> 16;
    return (u16)r;
}
__device__ __forceinline__ float bf2f(u16 u) {
    return __uint_as_float(((unsigned)u) << 16);
}

// ---------------------------------------------------------------------------
// Counting sort of edges by dst.
// ---------------------------------------------------------------------------
__global__ __launch_bounds__(256) void hist_kernel(
    const int* __restrict__ edst, int* __restrict__ cnt)
{
    int e = blockIdx.x * 256 + threadIdx.x;
    atomicAdd(&cnt[edst[e]], 1);
}

__global__ __launch_bounds__(256) void scan1_kernel(
    const int* __restrict__ cnt, int* __restrict__ base, int* __restrict__ csum)
{
    __shared__ int s[256];
    int tid = threadIdx.x, gid = blockIdx.x * 256 + tid;
    int v = cnt[gid]; s[tid] = v;
    for (int off = 1; off < 256; off <<= 1) {
        __syncthreads();
        int t = (tid >= off) ? s[tid - off] : 0;
        __syncthreads();
        s[tid] += t;
    }
    __syncthreads();
    base[gid] = s[tid] - v;                 // exclusive within chunk
    if (tid == 255) csum[blockIdx.x] = s[255];
}

__global__ __launch_bounds__(256) void scan2_kernel(int* __restrict__ csum)
{
    __shared__ int s[256];
    int tid = threadIdx.x;
    int v = (tid < 216) ? csum[tid] : 0;
    s[tid] = v;
    for (int off = 1; off < 256; off <<= 1) {
        __syncthreads();
        int t = (tid >= off) ? s[tid - off] : 0;
        __syncthreads();
        s[tid] += t;
    }
    __syncthreads();
    if (tid < 216) csum[tid] = s[tid] - v;  // exclusive across chunks
}

__global__ __launch_bounds__(256) void scatter_kernel(
    const int* __restrict__ edst, const int* __restrict__ esrc,
    int* __restrict__ base, const int* __restrict__ csum,
    int* __restrict__ perm, int* __restrict__ srcS, int* __restrict__ dstS)
{
    int e = blockIdx.x * 256 + threadIdx.x;
    int v = edst[e];
    int idx = csum[v >> 8] + atomicAdd(&base[v], 1);
    perm[idx] = e;
    srcS[idx] = esrc[e];
    dstS[idx] = v;
}

// ---------------------------------------------------------------------------
// Fused weight pack. Block ranges: [0,128) ew2 (hi+lo) | [128,132) pw1 |
// [132,136) pw2 | [136,148) wih | [148,160) whh.
// ---------------------------------------------------------------------------
__global__ __launch_bounds__(256) void pack_all(
    const float* __restrict__ ew2, const float* __restrict__ pw1,
    const float* __restrict__ pw2, const float* __restrict__ wih,
    const float* __restrict__ whh,
    u16* __restrict__ ew2h, u16* __restrict__ ew2l,
    u16* __restrict__ pw1h, u16* __restrict__ pw1l,
    u16* __restrict__ pw2h, u16* __restrict__ pw2l,
    u16* __restrict__ wihh, u16* __restrict__ wihl,
    u16* __restrict__ whhh, u16* __restrict__ whhl)
{
    int b = blockIdx.x;
    const float* src; u16 *dh, *dl; int ncols, trans, lb;
    if      (b < 128) { src = ew2; dh = ew2h; dl = ew2l; ncols = 1024; trans = 0; lb = b; }
    else if (b < 132) { src = pw1; dh = pw1h; dl = pw1l; ncols = 32;   trans = 0; lb = b - 128; }
    else if (b < 136) { src = pw2; dh = pw2h; dl = pw2l; ncols = 32;   trans = 0; lb = b - 132; }
    else if (b < 148) { src = wih; dh = wihh; dl = wihl; ncols = 32;   trans = 1; lb = b - 136; }
    else              { src = whh; dh = whhh; dl = whhl; ncols = 32;   trans = 1; lb = b - 148; }
    int idx = lb * 256 + threadIdx.x;
    int t = idx >> 9, rr = idx & 511, lane = rr >> 3, j = rr & 7;
    int k = (lane >> 4) * 8 + j;
    int n = t * 16 + (lane & 15);
    float v = trans ? src[n * 32 + k] : src[k * ncols + n];
    u16 hb = f2bf(v);
    dh[idx] = hb;
    dl[idx] = f2bf(v - bf2f(hb));
}

// ---------------------------------------------------------------------------
// Edge MLP layer 1 (sorted order via perm); writes hi + lo residual.
// ---------------------------------------------------------------------------
__global__ __launch_bounds__(256) void edgemlp_kernel(
    const float* __restrict__ er, const float* __restrict__ ew1,
    const float* __restrict__ eb1, const int* __restrict__ perm,
    u16* __restrict__ rbf, u16* __restrict__ rbfl)
{
    int gid = blockIdx.x * 256 + threadIdx.x;
    int e = gid >> 5, o = gid & 31;
    int pe = perm[e];
    f32x4 e4 = *(const f32x4*)(er + (size_t)pe * 4);
    float v = eb1[o] + e4[0] * ew1[o] + e4[1] * ew1[32 + o]
                     + e4[2] * ew1[64 + o] + e4[3] * ew1[96 + o];
    float vr = fmaxf(v, 0.f);
    u16 hb = f2bf(vr);
    rbf[gid]  = hb;
    rbfl[gid] = f2bf(vr - bf2f(hb));
}

// ---------------------------------------------------------------------------
// Node projection (also zeroes agg for step 0).
// ---------------------------------------------------------------------------
__global__ __launch_bounds__(256) void nodeproj_kernel(
    const float* __restrict__ x,
    const u16* __restrict__ pw1h, const u16* __restrict__ pw1l, const float* __restrict__ pb1,
    const u16* __restrict__ pw2h, const u16* __restrict__ pw2l, const float* __restrict__ pb2,
    float* __restrict__ st_f32, u16* __restrict__ st_hi, u16* __restrict__ st_lo,
    float* __restrict__ agg)
{
    __shared__ alignas(16) u16 t_hi[4][512];
    __shared__ alignas(16) u16 t_lo[4][512];
    int tid = threadIdx.x, wave = tid >> 6, lane = tid & 63;
    int quad = lane >> 4, col = lane & 15;
    int row0 = (blockIdx.x * 4 + wave) * 16;

    {   // zero agg for this block's 64 rows
        float* az = agg + (size_t)blockIdx.x * 64 * 32;
        f32x4 zz = {0.f, 0.f, 0.f, 0.f};
        *(f32x4*)(az + tid * 8)     = zz;
        *(f32x4*)(az + tid * 8 + 4) = zz;
    }

    const float* xp = x + (size_t)(row0 + col) * 32 + quad * 8;
    f32x4 xv0 = *(const f32x4*)(xp), xv1 = *(const f32x4*)(xp + 4);
    s16x8 ah, al;
#pragma unroll
    for (int i = 0; i < 4; ++i) {
        u16 h0 = f2bf(xv0[i]); ah[i] = (short)h0; al[i] = (short)f2bf(xv0[i] - bf2f(h0));
        u16 h1 = f2bf(xv1[i]); ah[4+i] = (short)h1; al[4+i] = (short)f2bf(xv1[i] - bf2f(h1));
    }
#pragma unroll
    for (int t = 0; t < 2; ++t) {
        s16x8 bh = *(const s16x8*)(pw1h + t * 512 + lane * 8);
        s16x8 bl = *(const s16x8*)(pw1l + t * 512 + lane * 8);
        f32x4 acc = {0,0,0,0};
        acc = MFMA(al, bh, acc, 0,0,0);
        acc = MFMA(ah, bl, acc, 0,0,0);
        acc = MFMA(ah, bh, acc, 0,0,0);
        float bias = pb1[t * 16 + col];
#pragma unroll
        for (int r = 0; r < 4; ++r) {
            float v = fmaxf(acc[r] + bias, 0.f);
            u16 hb = f2bf(v);
            int idx = (quad * 4 + r) * 32 + t * 16 + col;
            t_hi[wave][idx] = hb;
            t_lo[wave][idx] = f2bf(v - bf2f(hb));
        }
    }
    __syncthreads();
    s16x8 th = *(const s16x8*)(&t_hi[wave][col * 32 + quad * 8]);
    s16x8 tl = *(const s16x8*)(&t_lo[wave][col * 32 + quad * 8]);
#pragma unroll
    for (int t = 0; t < 2; ++t) {
        s16x8 bh = *(const s16x8*)(pw2h + t * 512 + lane * 8);
        s16x8 bl = *(const s16x8*)(pw2l + t * 512 + lane * 8);
        f32x4 acc = {0,0,0,0};
        acc = MFMA(tl, bh, acc, 0,0,0);
        acc = MFMA(th, bl, acc, 0,0,0);
        acc = MFMA(th, bh, acc, 0,0,0);
        float bias = pb2[t * 16 + col];
#pragma unroll
        for (int r = 0; r < 4; ++r) {
            float v = acc[r] + bias;
            int row = row0 + quad * 4 + r;
            int o = t * 16 + col;
            st_f32[(size_t)row * 32 + o] = v;
            u16 hb = f2bf(v);
            st_hi[(size_t)row * 32 + o] = hb;
            st_lo[(size_t)row * 32 + o] = f2bf(v - bf2f(hb));
        }
    }
}

// ---------------------------------------------------------------------------
// Message + scatter. 32 sorted edges/wave; We via 3-term bf16-split MFMA
// (ah*bh + al*bh + ah*bl); run-combined atomic scatter on sorted dst.
// ---------------------------------------------------------------------------
__global__ __launch_bounds__(256, 4) void msg_kernel(
    const u16* __restrict__ rbf, const u16* __restrict__ rbfl,
    const u16* __restrict__ ew2h, const u16* __restrict__ ew2l,
    const float* __restrict__ eb2, const float* __restrict__ state,
    const int* __restrict__ srcS, const int* __restrict__ dstS,
    float* __restrict__ agg)
{
    __shared__ alignas(16) float eb2_lds[1024];
    __shared__ alignas(16) float ns_lds[4][32 * 68];   // [wave][e*68 + b*32 + h]
    int tid = threadIdx.x;
    *(f32x4*)(eb2_lds + tid * 4) = *(const f32x4*)(eb2 + tid * 4);

    int wave = tid >> 6, lane = tid & 63;
    int quad = lane >> 4, col = lane & 15;
    int e0 = (blockIdx.x * 4 + wave) * 32;

    s16x8 afh0 = *(const s16x8*)(rbf  + (size_t)(e0 + col) * 32 + quad * 8);
    s16x8 afh1 = *(const s16x8*)(rbf  + (size_t)(e0 + 16 + col) * 32 + quad * 8);
    s16x8 afl0 = *(const s16x8*)(rbfl + (size_t)(e0 + col) * 32 + quad * 8);
    s16x8 afl1 = *(const s16x8*)(rbfl + (size_t)(e0 + 16 + col) * 32 + quad * 8);

    {   // stage gathered node feats: lane -> (el = lane>>1, b = lane&1)
        int el = lane >> 1, b = lane & 1;
        int src = srcS[e0 + el];
        const float* sp = state + ((size_t)b * NNODES + src) * 32;
        float* dp = &ns_lds[wave][el * 68 + b * 32];
#pragma unroll
        for (int c = 0; c < 8; ++c) *(f32x4*)(dp + c * 4) = *(const f32x4*)(sp + c * 4);
    }
    int dstA[2][4];
    {
        int4 d0 = *(const int4*)(dstS + e0 + quad * 4);
        int4 d1 = *(const int4*)(dstS + e0 + 16 + quad * 4);
        dstA[0][0]=d0.x; dstA[0][1]=d0.y; dstA[0][2]=d0.z; dstA[0][3]=d0.w;
        dstA[1][0]=d1.x; dstA[1][1]=d1.y; dstA[1][2]=d1.z; dstA[1][3]=d1.w;
    }
    __syncthreads();

    f32x2 mv[2][2][4];   // [frag][b][r] -> (o=col, o=16+col)
#pragma unroll
    for (int f = 0; f < 2; ++f)
#pragma unroll
        for (int b = 0; b < 2; ++b)
#pragma unroll
            for (int r = 0; r < 4; ++r) { mv[f][b][r].x = 0.f; mv[f][b][r].y = 0.f; }

    const float* nsw = &ns_lds[wave][0];
#pragma unroll 2
    for (int hh = 0; hh < 16; ++hh) {
        int h0 = hh * 2;
        f32x4 d[2][4];
#pragma unroll
        for (int t = 0; t < 4; ++t) {
            s16x8 bh = *(const s16x8*)(ew2h + (size_t)(4 * hh + t) * 512 + lane * 8);
            s16x8 bl = *(const s16x8*)(ew2l + (size_t)(4 * hh + t) * 512 + lane * 8);
            f32x4 z = {0,0,0,0};
            f32x4 a0 = MFMA(afl0, bh, z, 0,0,0);
            a0 = MFMA(afh0, bl, a0, 0,0,0);
            a0 = MFMA(afh0, bh, a0, 0,0,0);
            d[0][t] = a0;
            f32x4 a1 = MFMA(afl1, bh, z, 0,0,0);
            a1 = MFMA(afh1, bl, a1, 0,0,0);
            a1 = MFMA(afh1, bh, a1, 0,0,0);
            d[1][t] = a1;
        }
        f32x2 eb0 = { eb2_lds[h0 * 32 + col],      eb2_lds[h0 * 32 + 16 + col] };
        f32x2 eb1v= { eb2_lds[h0 * 32 + 32 + col], eb2_lds[h0 * 32 + 48 + col] };
#pragma unroll
        for (int f = 0; f < 2; ++f) {
#pragma unroll
            for (int r = 0; r < 4; ++r) {
                int e = f * 16 + quad * 4 + r;
                f32x2 n0 = *(const f32x2*)(nsw + e * 68 + h0);        // b=0
                f32x2 n1 = *(const f32x2*)(nsw + e * 68 + 32 + h0);   // b=1
                f32x2 w0 = { d[f][0][r] + eb0.x,  d[f][1][r] + eb0.y };   // h = h0
                f32x2 w1 = { d[f][2][r] + eb1v.x, d[f][3][r] + eb1v.y };  // h = h0+1
                mv[f][0][r] += n0.x * w0 + n0.y * w1;
                mv[f][1][r] += n1.x * w0 + n1.y * w1;
            }
        }
    }

    // run-combined atomic scatter (sorted dst => frequent equal neighbors)
#pragma unroll
    for (int f = 0; f < 2; ++f) {
#pragma unroll
        for (int b = 0; b < 2; ++b) {
            f32x2 acc = {0.f, 0.f};
#pragma unroll
            for (int r = 0; r < 4; ++r) {
                acc += mv[f][b][r];
                bool flush = (r == 3) || (dstA[f][r + 1] != dstA[f][r]);
                if (flush) {
                    float* bp = agg + ((size_t)b * NNODES + dstA[f][r]) * 32;
                    unsafeAtomicAdd(bp + col,      acc.x);
                    unsafeAtomicAdd(bp + 16 + col, acc.y);
                    acc.x = 0.f; acc.y = 0.f;
                }
            }
        }
    }
}

// ---------------------------------------------------------------------------
// GRU step, 32 rows/wave. NOTE: st_f32/st_hi/st_lo alias out_f32/out_hi/out_lo
// on non-final steps -- NO __restrict__ on these params (R2's restrict-alias
// UB let the compiler sink hid loads below the hnew store). hid is also
// hoisted into registers before the MFMA section.
// ---------------------------------------------------------------------------
__global__ __launch_bounds__(256) void gru_kernel(
    float* __restrict__ agg, const float* __restrict__ conv_b,
    const float* st_f32, const u16* st_hi, const u16* st_lo,
    const u16* __restrict__ wihh, const u16* __restrict__ wihl,
    const u16* __restrict__ whhh, const u16* __restrict__ whhl,
    const float* __restrict__ b_ih, const float* __restrict__ b_hh,
    float* out_f32, u16* out_hi, u16* out_lo)
{
    int tid = threadIdx.x, wave = tid >> 6, lane = tid & 63;
    int quad = lane >> 4, col = lane & 15;
    int row0 = (blockIdx.x * 4 + wave) * 32;

    const float* cb = conv_b + quad * 8;
    f32x4 cb0 = *(const f32x4*)cb, cb1 = *(const f32x4*)(cb + 4);

    s16x8 anh[2], anl[2], ahh[2], ahl[2];
#pragma unroll
    for (int f = 0; f < 2; ++f) {
        size_t ro = (size_t)(row0 + f * 16 + col) * 32 + quad * 8;
        float* ap = agg + ro;
        f32x4 av0 = *(const f32x4*)ap, av1 = *(const f32x4*)(ap + 4);
        f32x4 zz = {0.f,0.f,0.f,0.f};
        *(f32x4*)ap = zz; *(f32x4*)(ap + 4) = zz;
#pragma unroll
        for (int i = 0; i < 4; ++i) {
            float v0 = fmaxf(av0[i] + cb0[i], 0.f);
            float v1 = fmaxf(av1[i] + cb1[i], 0.f);
            u16 h0 = f2bf(v0); anh[f][i] = (short)h0;   anl[f][i] = (short)f2bf(v0 - bf2f(h0));
            u16 h1 = f2bf(v1); anh[f][4+i] = (short)h1; anl[f][4+i] = (short)f2bf(v1 - bf2f(h1));
        }
        ahh[f] = *(const s16x8*)(st_hi + ro);
        ahl[f] = *(const s16x8*)(st_lo + ro);
    }

    // hoist hid loads (before any aliased stores can be scheduled)
    float hidv[2][4][2];
#pragma unroll
    for (int f = 0; f < 2; ++f)
#pragma unroll
        for (int r = 0; r < 4; ++r) {
            int row = row0 + f * 16 + quad * 4 + r;
            hidv[f][r][0] = st_f32[(size_t)row * 32 + col];
            hidv[f][r][1] = st_f32[(size_t)row * 32 + 16 + col];
        }

    f32x4 gx[2][6], gh[2][6];
#pragma unroll
    for (int t = 0; t < 6; ++t) {
        s16x8 bh = *(const s16x8*)(wihh + t * 512 + lane * 8);
        s16x8 bl = *(const s16x8*)(wihl + t * 512 + lane * 8);
        s16x8 ch = *(const s16x8*)(whhh + t * 512 + lane * 8);
        s16x8 cl = *(const s16x8*)(whhl + t * 512 + lane * 8);
#pragma unroll
        for (int f = 0; f < 2; ++f) {
            f32x4 a = {0,0,0,0};
            a = MFMA(anl[f], bh, a, 0,0,0);
            a = MFMA(anh[f], bl, a, 0,0,0);
            a = MFMA(anh[f], bh, a, 0,0,0);
            gx[f][t] = a;
            f32x4 c = {0,0,0,0};
            c = MFMA(ahl[f], ch, c, 0,0,0);
            c = MFMA(ahh[f], cl, c, 0,0,0);
            c = MFMA(ahh[f], ch, c, 0,0,0);
            gh[f][t] = c;
        }
    }
    float bihv[6], bhhv[6];
#pragma unroll
    for (int t = 0; t < 6; ++t) { bihv[t] = b_ih[t * 16 + col]; bhhv[t] = b_hh[t * 16 + col]; }

#pragma unroll
    for (int f = 0; f < 2; ++f) {
#pragma unroll
        for (int r = 0; r < 4; ++r) {
            int row = row0 + f * 16 + quad * 4 + r;
#pragma unroll
            for (int oh = 0; oh < 2; ++oh) {
                int o = oh * 16 + col;
                float hid = hidv[f][r][oh];
                float sr = (gx[f][oh][r] + bihv[oh]) + (gh[f][oh][r] + bhhv[oh]);
                float sz = (gx[f][2+oh][r] + bihv[2+oh]) + (gh[f][2+oh][r] + bhhv[2+oh]);
                float gxn = gx[f][4+oh][r] + bihv[4+oh];
                float ghn = gh[f][4+oh][r] + bhhv[4+oh];
                float rr = 1.f / (1.f + __expf(-sr));
                float zz = 1.f / (1.f + __expf(-sz));
                float narg = gxn + rr * ghn;
                float ex = __expf(2.f * narg);
                float nn = (ex - 1.f) / (ex + 1.f);
                float hnew = (1.f - zz) * nn + zz * hid;
                out_f32[(size_t)row * 32 + o] = hnew;
                u16 hb = f2bf(hnew);
                out_hi[(size_t)row * 32 + o] = hb;
                out_lo[(size_t)row * 32 + o] = f2bf(hnew - bf2f(hb));
            }
        }
    }
}

// ---------------------------------------------------------------------------
extern "C" void kernel_launch(void* const* d_in, const int* in_sizes, int n_in,
                              void* d_out, int out_size, void* d_ws, size_t ws_size,
                              hipStream_t stream)
{
    const float* x      = (const float*)d_in[0];
    const float* er     = (const float*)d_in[1];
    const float* pw1    = (const float*)d_in[2];
    const float* pb1    = (const float*)d_in[3];
    const float* pw2    = (const float*)d_in[4];
    const float* pb2    = (const float*)d_in[5];
    const float* ew1    = (const float*)d_in[6];
    const float* eb1    = (const float*)d_in[7];
    const float* ew2    = (const float*)d_in[8];
    const float* eb2    = (const float*)d_in[9];
    const float* conv_b = (const float*)d_in[10];
    const float* wih    = (const float*)d_in[11];
    const float* whh    = (const float*)d_in[12];
    const float* bih    = (const float*)d_in[13];
    const float* bhh    = (const float*)d_in[14];
    const int*   esrc   = (const int*)d_in[15];
    const int*   edst   = (const int*)d_in[16];
    float* out = (float*)d_out;

    char* ws = (char*)d_ws;
    size_t off = 0;
    auto alloc = [&](size_t bytes) -> void* {
        void* p = ws + off;
        off = (off + bytes + 255) & ~(size_t)255;
        return p;
    };
    u16*   rbf    = (u16*)  alloc((size_t)NEDGES * 32 * 2);
    u16*   rbfl   = (u16*)  alloc((size_t)NEDGES * 32 * 2);
    float* st_f32 = (float*)alloc((size_t)ROWS * 32 * 4);
    u16*   st_hi  = (u16*)  alloc((size_t)ROWS * 32 * 2);
    u16*   st_lo  = (u16*)  alloc((size_t)ROWS * 32 * 2);
    float* agg    = (float*)alloc((size_t)ROWS * 32 * 4);
    u16*   ew2fh  = (u16*)  alloc(64 * 512 * 2);
    u16*   ew2fl  = (u16*)  alloc(64 * 512 * 2);
    u16*   pw1h   = (u16*)  alloc(2 * 512 * 2);
    u16*   pw1l   = (u16*)  alloc(2 * 512 * 2);
    u16*   pw2h   = (u16*)  alloc(2 * 512 * 2);
    u16*   pw2l   = (u16*)  alloc(2 * 512 * 2);
    u16*   wihhf  = (u16*)  alloc(6 * 512 * 2);
    u16*   wihlf  = (u16*)  alloc(6 * 512 * 2);
    u16*   whhhf  = (u16*)  alloc(6 * 512 * 2);
    u16*   whhlf  = (u16*)  alloc(6 * 512 * 2);
    int*   cnt    = (int*)  alloc((size_t)NNODES * 4);
    int*   base   = (int*)  alloc((size_t)NNODES * 4);
    int*   csum   = (int*)  alloc(256 * 4);
    int*   perm   = (int*)  alloc((size_t)NEDGES * 4);
    int*   srcS   = (int*)  alloc((size_t)NEDGES * 4);
    int*   dstS   = (int*)  alloc((size_t)NEDGES * 4);
    (void)in_sizes; (void)n_in; (void)out_size; (void)ws_size;

    // ---- counting sort of edges by dst ----
    hipMemsetAsync(cnt, 0, (size_t)NNODES * 4, stream);
    hist_kernel   <<<NEDGES / 256, 256, 0, stream>>>(edst, cnt);
    scan1_kernel  <<<NNODES / 256, 256, 0, stream>>>(cnt, base, csum);
    scan2_kernel  <<<1,            256, 0, stream>>>(csum);
    scatter_kernel<<<NEDGES / 256, 256, 0, stream>>>(edst, esrc, base, csum, perm, srcS, dstS);

    // ---- weight packing + precompute ----
    pack_all<<<160, 256, 0, stream>>>(ew2, pw1, pw2, wih, whh,
                                      ew2fh, ew2fl, pw1h, pw1l, pw2h, pw2l,
                                      wihhf, wihlf, whhhf, whhlf);
    edgemlp_kernel<<<NEDGES * 32 / 256, 256, 0, stream>>>(er, ew1, eb1, perm, rbf, rbfl);
    nodeproj_kernel<<<ROWS / 64, 256, 0, stream>>>(x, pw1h, pw1l, pb1, pw2h, pw2l, pb2,
                                                   st_f32, st_hi, st_lo, agg);

    // ---- 3 message-passing + GRU steps ----
    for (int s = 0; s < 3; ++s) {
        msg_kernel<<<NEDGES / 128, 256, 0, stream>>>(rbf, rbfl, ew2fh, ew2fl, eb2,
                                                     st_f32, srcS, dstS, agg);
        float* of = (s == 2) ? out : st_f32;
        gru_kernel<<<ROWS / 128, 256, 0, stream>>>(agg, conv_b, st_f32, st_hi, st_lo,
                                                   wihhf, wihlf, whhhf, whhlf, bih, bhh,
                                                   of, st_hi, st_lo);
    }
}